// Round 4
// baseline (281.913 us; speedup 1.0000x reference)
//
#include <hip/hip_runtime.h>
#include <hip/hip_cooperative_groups.h>

namespace cg = cooperative_groups;

#define PP 96
#define NB (PP*PP)          // 9216
#define NW6 (NB/64)         // 144 wave-masks
#define PROB_THR 0.9f
#define IOU_THR 0.5f
#define FAST_MAX_M 2048     // fast sweep: W <= 32
#define NBLK 256
#define NTHR 256

typedef unsigned long long u64;

__device__ __forceinline__ int iou_hit(float ix1, float iy1, float ix2, float iy2, float iar,
                                       float jx1, float jy1, float jx2, float jy2, float jar)
{
    float xx1 = fmaxf(ix1, jx1), yy1 = fmaxf(iy1, jy1);
    float xx2 = fminf(ix2, jx2), yy2 = fminf(iy2, jy2);
    float iw = fmaxf(__fsub_rn(xx2, xx1), 0.0f);
    float ih = fmaxf(__fsub_rn(yy2, yy1), 0.0f);
    float inter = __fmul_rn(iw, ih);
    float uni = __fsub_rn(__fadd_rn(iar, jar), inter);
    return (uni > 0.0f && __fdiv_rn(inter, uni) > IOU_THR) ? 1 : 0;
}

// Bit-identical decode (no FMA contraction; rintf == round-half-even).
__device__ __forceinline__ void decode_box(const float* __restrict__ x, int n,
                                           float& X1, float& Y1, float& X2, float& Y2)
{
    float xv = x[NB + n];
    float yv = x[2 * NB + n];
    float wv = x[3 * NB + n];
    float hv = x[4 * NB + n];
    int i = n / PP;
    int j = n - i * PP;
    float bx = __fadd_rn(__fmul_rn(xv, 16.0f), (float)i * 16.0f);
    float by = __fadd_rn(__fmul_rn(yv, 16.0f), (float)j * 16.0f);
    float bw = __fmul_rn(wv, 1536.0f);
    float bh = __fmul_rn(hv, 1536.0f);
    X1 = rintf(bx);
    Y1 = rintf(by);
    X2 = rintf(__fadd_rn(bw, bx));
    Y2 = rintf(__fadd_rn(bh, by));
}

__global__ void __launch_bounds__(NTHR, 1) k_all(
    const float* __restrict__ x, float* __restrict__ out,
    u64* __restrict__ cmask, u64* __restrict__ kslot, u64* __restrict__ dkey,
    float* __restrict__ ss,
    float* __restrict__ sx1, float* __restrict__ sy1,
    float* __restrict__ sx2, float* __restrict__ sy2,
    u64* __restrict__ adj, long long cap_words, int* __restrict__ counter)
{
    __shared__ u64 shmem[2048];          // 16 KB: rank tile / sweep dbuf / keep words
    cg::grid_group grid = cg::this_grid();
    const int tid  = threadIdx.x;
    const int gtid = blockIdx.x * NTHR + tid;
    const int lane = tid & 63;

    // ---- Phase A: validity ballot + packed keys; spare threads zero out[] ----
    if (gtid < NB) {
        float s = x[gtid];
        int valid = (s > PROB_THR) ? 1 : 0;
        u64 m = __ballot(valid);
        if (valid)
            kslot[gtid] = ((u64)__float_as_uint(s) << 32) | (u64)(NB - 1 - gtid);
        if (lane == 0) cmask[gtid >> 6] = m;
    } else {
        int q = gtid - NB;                       // 56320 spare threads
        if (q < (6 * NB) / 4)                    // 13824 float4s = 55296 floats
            *(float4*)(out + q * 4) = make_float4(0.f, 0.f, 0.f, 0.f);
    }
    grid.sync();

    // ---- Phase B1: dense scatter (prefix over wave masks); thread 0 writes M ----
    if (gtid < NB) {
        int w = gtid >> 6;
        u64 mask = cmask[w];
        if ((mask >> lane) & 1ull) {
            int pos = __popcll(mask & ((1ull << lane) - 1ull));
            for (int w2 = 0; w2 < w; ++w2) pos += __popcll(cmask[w2]);
            dkey[pos] = kslot[gtid];
        }
        if (gtid == 0) {
            int tot = 0;
            for (int w2 = 0; w2 < NW6; ++w2) tot += __popcll(cmask[w2]);
            counter[0] = tot;
        }
    }
    grid.sync();

    int M = counter[0];

    // ---- Phase B2: rank (counting sort over unique keys) + sorted scatter ----
    if (blockIdx.x < (NB / NTHR)) {              // 36 blocks cover t < NB >= M
        int t = gtid;
        u64 mykey = (t < M) ? dkey[t] : 0ull;
        int r = 0;
        for (int q0 = 0; q0 < M; q0 += 2048) {
            int cnt = M - q0; if (cnt > 2048) cnt = 2048;
            __syncthreads();
            for (int q = tid; q < cnt; q += NTHR) shmem[q] = dkey[q0 + q];
            __syncthreads();
            if (t < M) {
                #pragma unroll 8
                for (int q = 0; q < cnt; ++q) r += (shmem[q] > mykey) ? 1 : 0;
            }
        }
        if (t < M) {
            int n = NB - 1 - (int)(mykey & 0xFFFFFFFFull);
            float X1, Y1, X2, Y2;
            decode_box(x, n, X1, Y1, X2, Y2);
            ss[r] = __uint_as_float((unsigned)(mykey >> 32));
            sx1[r] = X1; sy1[r] = Y1; sx2[r] = X2; sy2[r] = Y2;
        }
    }
    grid.sync();

    const int W = (M + 63) >> 6;
    const long long R = (long long)(((M + 31) >> 5) << 5);
    const bool fast = (M <= FAST_MAX_M) && (R * W + 64 <= cap_words);

    // ---- Phase C: adjacency bit matrix, one wave per sorted row ----
    if (fast) {
        int wid = (blockIdx.x << 2) | (tid >> 6);
        for (int i = wid; i < M; i += NBLK * 4) {
            float ix1 = sx1[i], iy1 = sy1[i], ix2 = sx2[i], iy2 = sy2[i];
            float iar = __fmul_rn(__fsub_rn(ix2, ix1), __fsub_rn(iy2, iy1));
            for (int k = 0; k < W; ++k) {
                int j = (k << 6) + lane;
                int inb = (j < M);
                int jc = inb ? j : (M - 1);
                float jx1 = sx1[jc], jy1 = sy1[jc], jx2 = sx2[jc], jy2 = sy2[jc];
                float jar = __fmul_rn(__fsub_rn(jx2, jx1), __fsub_rn(jy2, jy1));
                int hit = inb && iou_hit(ix1, iy1, ix2, iy2, iar, jx1, jy1, jx2, jy2, jar);
                u64 mm = __ballot(hit);
                if (lane == 0) adj[(size_t)i * W + k] = mm;
            }
        }
    }
    grid.sync();

    // ---- Phase D: sweep (block 0) + parallel emit ----
    if (blockIdx.x != 0) return;

    if (fast) {
        if (tid < 64) {
            int wl = (lane < W) ? lane : 0;
            u64 sup = 0ull, dec = 0ull, mykw = 0ull;
            int nrb = (M + 31) >> 5;
            int nw = (32 * W + 63) >> 6;          // <=16 lane-sliced u64 regs
            u64 pre[16];
            if (nrb > 0) {                        // prologue: stage row-block 0
                for (int q = 0; q < nw; ++q) pre[q] = adj[q * 64 + lane];
                for (int q = 0; q < nw; ++q) shmem[q * 64 + lane] = pre[q];
            }
            for (int rb = 0; rb < nrb; ++rb) {
                int c = rb >> 1;
                u64* bp = shmem + (size_t)(rb & 1) * 1024;
                bool pf = (rb + 1 < nrb);
                if (pf) {                         // issue next-block loads early
                    size_t boff = (size_t)(rb + 1) * 32 * W;
                    for (int q = 0; q < nw; ++q) pre[q] = adj[boff + q * 64 + lane];
                }
                if (!(rb & 1)) dec = (rb == 0) ? 0ull : (u64)__shfl((unsigned long long)sup, c);
                int rem = M - (c << 6);
                if (rem < 64) dec |= (~0ull) << rem;
                int sh = (rb & 1) << 5;
                u64 kw = 0ull;
                for (int sc = 0; sc < 4; ++sc) {
                    u64 colb[8], rowb[8];
                    #pragma unroll
                    for (int t = 0; t < 8; ++t) {
                        int row = sc * 8 + t;
                        colb[t] = bp[row * W + c];
                        rowb[t] = bp[row * W + wl];
                    }
                    #pragma unroll
                    for (int t = 0; t < 8; ++t) {
                        int tt = sc * 8 + t;
                        u64 b = (dec >> (tt + sh)) & 1ull;
                        u64 m = b - 1ull;         // ~0 if kept, 0 if suppressed
                        dec |= colb[t] & m;
                        sup |= rowb[t] & m;
                        kw  |= m & (1ull << tt);
                    }
                }
                mykw |= (lane == c) ? (kw << sh) : 0ull;
                if (pf) {                         // drain prefetch into other buffer
                    u64* dst = shmem + (size_t)((rb + 1) & 1) * 1024;
                    for (int q = 0; q < nw; ++q) dst[q * 64 + lane] = pre[q];
                }
            }
            shmem[lane] = mykw;                   // keep word w in shmem[w]
        }
    } else {
        // Slow fallback (any M <= NB; never hit for this distribution).
        if (tid < 64) {
            u64 kbs[3] = {0ull, 0ull, 0ull};
            for (int i = 0; i < M; ++i) {
                float ix1 = sx1[i], iy1 = sy1[i], ix2 = sx2[i], iy2 = sy2[i];
                float iar = __fmul_rn(__fsub_rn(ix2, ix1), __fsub_rn(iy2, iy1));
                int hit = 0;
                int nk = (i > lane) ? ((i - lane + 63) >> 6) : 0;
                for (int w = 0; w < 3 && !hit; ++w) {
                    int klim = nk - (w << 6);
                    if (klim <= 0) break;
                    u64 bits = kbs[w];
                    if (klim < 64) bits &= ((1ull << klim) - 1ull);
                    while (bits) {
                        int kk = __builtin_ctzll(bits);
                        bits &= bits - 1ull;
                        int jj = lane + (((w << 6) + kk) << 6);
                        float jx1 = sx1[jj], jy1 = sy1[jj], jx2 = sx2[jj], jy2 = sy2[jj];
                        float jar = __fmul_rn(__fsub_rn(jx2, jx1), __fsub_rn(jy2, jy1));
                        if (iou_hit(ix1, iy1, ix2, iy2, iar, jx1, jy1, jx2, jy2, jar)) { hit = 1; break; }
                    }
                }
                int suppressed = __any(hit);
                if (!suppressed && lane == (i & 63)) kbs[(i >> 6) >> 6] |= 1ull << ((i >> 6) & 63);
            }
            int NWrd = (M + 63) >> 6;             // transpose to keep words
            for (int wd = 0; wd < NWrd; ++wd) {
                u64 bit = (kbs[wd >> 6] >> (wd & 63)) & 1ull;
                u64 word = __ballot(bit != 0);
                if (lane == 0) shmem[wd] = word;
            }
        }
    }
    __syncthreads();

    for (int i = tid; i < M; i += NTHR) {
        if ((shmem[i >> 6] >> (i & 63)) & 1ull) {
            float a = sx1[i], b = sy1[i], c2 = sx2[i], d = sy2[i];
            out[i * 5 + 0] = ss[i];
            out[i * 5 + 1] = a;
            out[i * 5 + 2] = b;
            out[i * 5 + 3] = __fsub_rn(c2, a);
            out[i * 5 + 4] = __fsub_rn(d, b);
            out[5 * NB + i] = 1.0f;
        }
    }
}

extern "C" void kernel_launch(void* const* d_in, const int* in_sizes, int n_in,
                              void* d_out, int out_size, void* d_ws, size_t ws_size,
                              hipStream_t stream) {
    const float* x = (const float*)d_in[0];
    float* out = (float*)d_out;

    // Workspace layout (proven ws_size >= ~520 KB from R2; this uses ~450 KB):
    // [0,16) counter | cmask u64[144] | kslot u64[NB] | dkey u64[NB]
    // | ss,sx1,sy1,sx2,sy2 f32[NB] x5 | adj bit matrix
    char* ws = (char*)d_ws;
    int* counter = (int*)ws;
    u64* cmask = (u64*)(ws + 16);
    u64* kslot = cmask + NW6;
    u64* dkey  = kslot + NB;
    float* fb  = (float*)(dkey + NB);
    float* ss  = fb + 0 * NB;
    float* sx1 = fb + 1 * NB;
    float* sy1 = fb + 2 * NB;
    float* sx2 = fb + 3 * NB;
    float* sy2 = fb + 4 * NB;
    size_t adj_off = 16 + (size_t)NW6 * 8 + (size_t)2 * NB * 8 + (size_t)5 * NB * 4;
    u64* adj = (u64*)(ws + adj_off);
    long long cap_words = (ws_size > adj_off) ? (long long)((ws_size - adj_off) / 8) : 0;

    void* args[] = { (void*)&x, (void*)&out, (void*)&cmask, (void*)&kslot, (void*)&dkey,
                     (void*)&ss, (void*)&sx1, (void*)&sy1, (void*)&sx2, (void*)&sy2,
                     (void*)&adj, (void*)&cap_words, (void*)&counter };
    hipLaunchCooperativeKernel((void*)k_all, dim3(NBLK), dim3(NTHR), args, 0, stream);
}

// Round 5
// 203.136 us; speedup vs baseline: 1.3878x; 1.3878x over previous
//
#include <hip/hip_runtime.h>

#define PP 96
#define NB (PP*PP)          // 9216
#define PROB_THR 0.9f
#define IOU_THR 0.5f
#define FAST_MAX_M 2048     // fast path: W <= 32
#define KS_BLOCKS 512       // 2048 producer waves

typedef unsigned long long u64;

__device__ __forceinline__ int iou_hit(float ix1, float iy1, float ix2, float iy2, float iar,
                                       float jx1, float jy1, float jx2, float jy2, float jar)
{
    float xx1 = fmaxf(ix1, jx1), yy1 = fmaxf(iy1, jy1);
    float xx2 = fminf(ix2, jx2), yy2 = fminf(iy2, jy2);
    float iw = fmaxf(__fsub_rn(xx2, xx1), 0.0f);
    float ih = fmaxf(__fsub_rn(yy2, yy1), 0.0f);
    float inter = __fmul_rn(iw, ih);
    float uni = __fsub_rn(__fadd_rn(iar, jar), inter);
    return (uni > 0.0f && __fdiv_rn(inter, uni) > IOU_THR) ? 1 : 0;
}

// Bit-identical decode (no FMA contraction; rintf == round-half-even == jnp.round).
__device__ __forceinline__ void decode_box(const float* __restrict__ x, int n,
                                           float& X1, float& Y1, float& X2, float& Y2)
{
    float xv = x[NB + n];
    float yv = x[2 * NB + n];
    float wv = x[3 * NB + n];
    float hv = x[4 * NB + n];
    int i = n / PP;
    int j = n - i * PP;
    float bx = __fadd_rn(__fmul_rn(xv, 16.0f), (float)i * 16.0f);
    float by = __fadd_rn(__fmul_rn(yv, 16.0f), (float)j * 16.0f);
    float bw = __fmul_rn(wv, 1536.0f);
    float bh = __fmul_rn(hv, 1536.0f);
    X1 = rintf(bx);
    Y1 = rintf(by);
    X2 = rintf(__fadd_rn(bw, bx));
    Y2 = rintf(__fadd_rn(bh, by));
}

// ---------------------------------------------------------------------------
// k_rank: 576 blocks x 256. Block stages the score plane (36 KB) in LDS.
// Wave handles 4 candidates; for each valid one, lanes count valid boxes with
// strictly greater key (score desc, index asc — stable argsort(-key)), then
// lane 0 decodes the box and scatters to sorted arrays at rank r.
// Block 0 wave 0 additionally writes M and zeroes the `done` flag for k_nms.
// ---------------------------------------------------------------------------
__global__ void __launch_bounds__(256) k_rank(const float* __restrict__ x,
        float* __restrict__ ss,
        float* __restrict__ sx1, float* __restrict__ sy1,
        float* __restrict__ sx2, float* __restrict__ sy2,
        int* __restrict__ counter, int* __restrict__ done)
{
    __shared__ float lsc[NB];                 // 36 KB score plane
    const int tid = threadIdx.x;
    for (int q = tid; q < NB; q += 256) lsc[q] = x[q];
    __syncthreads();

    const int lane = tid & 63;
    const int wv = tid >> 6;
    const int base = (blockIdx.x * 4 + wv) * 4;   // 4 candidates per wave

    for (int c = 0; c < 4; ++c) {
        int n = base + c;
        float sn = lsc[n];                    // broadcast LDS read (uniform)
        if (!(sn > PROB_THR)) continue;       // wave-uniform branch
        int cnt = 0;
        for (int q = lane; q < NB; q += 64) {
            float sq = lsc[q];
            bool g = (sq > PROB_THR) && ((sq > sn) || (sq == sn && q < n));
            cnt += g ? 1 : 0;
        }
        #pragma unroll
        for (int off = 32; off; off >>= 1) cnt += __shfl_xor(cnt, off);
        if (lane == 0) {
            float X1, Y1, X2, Y2;
            decode_box(x, n, X1, Y1, X2, Y2);
            ss[cnt] = sn;
            sx1[cnt] = X1; sy1[cnt] = Y1; sx2[cnt] = X2; sy2[cnt] = Y2;
        }
    }

    if (blockIdx.x == 0 && wv == 0) {
        int cnt = 0;
        for (int q = lane; q < NB; q += 64) cnt += (lsc[q] > PROB_THR) ? 1 : 0;
        #pragma unroll
        for (int off = 32; off; off >>= 1) cnt += __shfl_xor(cnt, off);
        if (lane == 0) { counter[0] = cnt; done[0] = 0; }
    }
}

// ---------------------------------------------------------------------------
// k_nms: 512 blocks x 256 (2048 waves).
// Producers: wave i (< M) builds adjacency row i (ballot bits), publishes via
// agent-scope atomic stores, then __threadfence + release-add on `done`.
// Block 0: after producing its own rows, wave 0 acquire-spins to done==M,
// runs the LDS double-buffered register sweep (agent-scope adj loads), then
// all 256 threads emit EVERY output row (zeros for non-kept) + keeps flags.
// Single-consumer spin: deadlock-free; no cross-XCD L2 coherence assumed.
// ---------------------------------------------------------------------------
__global__ void __launch_bounds__(256) k_nms(const float* __restrict__ x,
        float* __restrict__ out,
        const float* __restrict__ ss,
        const float* __restrict__ sx1, const float* __restrict__ sy1,
        const float* __restrict__ sx2, const float* __restrict__ sy2,
        u64* __restrict__ adj, long long cap_words,
        const int* __restrict__ counter, int* __restrict__ done)
{
    __shared__ u64 shmem[2048];               // 16 KB: sweep dbuf + keep words
    int M = counter[0]; if (M > NB) M = NB;
    const int W = (M + 63) >> 6;
    const long long R = (long long)(((M + 31) >> 5) << 5);
    const bool fast = (M <= FAST_MAX_M) && (R * W + 64 <= cap_words);
    const int tid = threadIdx.x, lane = tid & 63;
    const int wid = (blockIdx.x << 2) | (tid >> 6);

    if (fast && wid < M) {
        int i = wid;
        float ix1 = sx1[i], iy1 = sy1[i], ix2 = sx2[i], iy2 = sy2[i];
        float iar = __fmul_rn(__fsub_rn(ix2, ix1), __fsub_rn(iy2, iy1));
        for (int k = 0; k < W; ++k) {
            int j = (k << 6) + lane;
            int inb = (j < M);
            int jc = inb ? j : (M - 1);
            float jx1 = sx1[jc], jy1 = sy1[jc], jx2 = sx2[jc], jy2 = sy2[jc];
            float jar = __fmul_rn(__fsub_rn(jx2, jx1), __fsub_rn(jy2, jy1));
            int hit = inb && iou_hit(ix1, iy1, ix2, iy2, iar, jx1, jy1, jx2, jy2, jar);
            u64 mm = __ballot(hit);
            if (lane == 0)
                __hip_atomic_store(&adj[(size_t)i * W + k], mm,
                                   __ATOMIC_RELAXED, __HIP_MEMORY_SCOPE_AGENT);
        }
        __threadfence();
        if (lane == 0)
            __hip_atomic_fetch_add(done, 1, __ATOMIC_RELEASE, __HIP_MEMORY_SCOPE_AGENT);
    }
    if (blockIdx.x != 0) return;

    if (fast) {
        if (tid < 64) {
            while (__hip_atomic_load(done, __ATOMIC_ACQUIRE, __HIP_MEMORY_SCOPE_AGENT) < M)
                __builtin_amdgcn_s_sleep(2);
            int wl = (lane < W) ? lane : 0;
            u64 sup = 0ull, dec = 0ull, mykw = 0ull;
            int nrb = (M + 31) >> 5;
            int nw = (32 * W + 63) >> 6;          // <= 16 lane-sliced u64 regs
            u64 pre[16];
            if (nrb > 0) {
                for (int q = 0; q < nw; ++q)
                    pre[q] = __hip_atomic_load(&adj[q * 64 + lane],
                                               __ATOMIC_RELAXED, __HIP_MEMORY_SCOPE_AGENT);
                for (int q = 0; q < nw; ++q) shmem[q * 64 + lane] = pre[q];
            }
            for (int rb = 0; rb < nrb; ++rb) {
                int c = rb >> 1;
                u64* bp = shmem + (size_t)(rb & 1) * 1024;
                bool pf = (rb + 1 < nrb);
                if (pf) {
                    size_t boff = (size_t)(rb + 1) * 32 * W;
                    for (int q = 0; q < nw; ++q)
                        pre[q] = __hip_atomic_load(&adj[boff + q * 64 + lane],
                                                   __ATOMIC_RELAXED, __HIP_MEMORY_SCOPE_AGENT);
                }
                if (!(rb & 1)) dec = (rb == 0) ? 0ull : (u64)__shfl((unsigned long long)sup, c);
                int rem = M - (c << 6);
                if (rem < 64) dec |= (~0ull) << rem;
                int sh = (rb & 1) << 5;
                u64 kw = 0ull;
                for (int sc = 0; sc < 4; ++sc) {
                    u64 colb[8], rowb[8];
                    #pragma unroll
                    for (int t = 0; t < 8; ++t) {
                        int row = sc * 8 + t;
                        colb[t] = bp[row * W + c];
                        rowb[t] = bp[row * W + wl];
                    }
                    #pragma unroll
                    for (int t = 0; t < 8; ++t) {
                        int tt = sc * 8 + t;
                        u64 b = (dec >> (tt + sh)) & 1ull;
                        u64 m = b - 1ull;         // ~0 if kept, 0 if suppressed
                        dec |= colb[t] & m;
                        sup |= rowb[t] & m;
                        kw  |= m & (1ull << tt);
                    }
                }
                mykw |= (lane == c) ? (kw << sh) : 0ull;
                if (pf) {
                    u64* dst = shmem + (size_t)((rb + 1) & 1) * 1024;
                    for (int q = 0; q < nw; ++q) dst[q * 64 + lane] = pre[q];
                }
            }
            shmem[lane] = mykw;                   // keep word w in shmem[w]
        }
    } else {
        // Slow fallback (any M <= NB; no adjacency, direct IoU; never hit here).
        if (tid < 64) {
            u64 kbs[3] = {0ull, 0ull, 0ull};
            for (int i = 0; i < M; ++i) {
                float ix1 = sx1[i], iy1 = sy1[i], ix2 = sx2[i], iy2 = sy2[i];
                float iar = __fmul_rn(__fsub_rn(ix2, ix1), __fsub_rn(iy2, iy1));
                int hit = 0;
                int nk = (i > lane) ? ((i - lane + 63) >> 6) : 0;
                for (int w = 0; w < 3 && !hit; ++w) {
                    int klim = nk - (w << 6);
                    if (klim <= 0) break;
                    u64 bits = kbs[w];
                    if (klim < 64) bits &= ((1ull << klim) - 1ull);
                    while (bits) {
                        int kk = __builtin_ctzll(bits);
                        bits &= bits - 1ull;
                        int jj = lane + (((w << 6) + kk) << 6);
                        float jx1 = sx1[jj], jy1 = sy1[jj], jx2 = sx2[jj], jy2 = sy2[jj];
                        float jar = __fmul_rn(__fsub_rn(jx2, jx1), __fsub_rn(jy2, jy1));
                        if (iou_hit(ix1, iy1, ix2, iy2, iar, jx1, jy1, jx2, jy2, jar)) { hit = 1; break; }
                    }
                }
                int suppressed = __any(hit);
                if (!suppressed && lane == (i & 63)) kbs[(i >> 6) >> 6] |= 1ull << ((i >> 6) & 63);
            }
            int NWrd = (M + 63) >> 6;             // transpose to keep words
            for (int wd = 0; wd < NWrd; ++wd) {
                u64 bit = (kbs[wd >> 6] >> (wd & 63)) & 1ull;
                u64 word = __ballot(bit != 0);
                if (lane == 0) shmem[wd] = word;
            }
        }
    }
    __syncthreads();

    // Emit ALL rows: kept -> [s, x1, y1, w, h] + 1.0; else zeros.
    for (int i = tid; i < NB; i += 256) {
        bool kept = (i < M) && ((shmem[i >> 6] >> (i & 63)) & 1ull);
        if (kept) {
            float a = sx1[i], b = sy1[i], c2 = sx2[i], d = sy2[i];
            out[i * 5 + 0] = ss[i];
            out[i * 5 + 1] = a;
            out[i * 5 + 2] = b;
            out[i * 5 + 3] = __fsub_rn(c2, a);
            out[i * 5 + 4] = __fsub_rn(d, b);
            out[5 * NB + i] = 1.0f;
        } else {
            out[i * 5 + 0] = 0.0f;
            out[i * 5 + 1] = 0.0f;
            out[i * 5 + 2] = 0.0f;
            out[i * 5 + 3] = 0.0f;
            out[i * 5 + 4] = 0.0f;
            out[5 * NB + i] = 0.0f;
        }
    }
}

extern "C" void kernel_launch(void* const* d_in, const int* in_sizes, int n_in,
                              void* d_out, int out_size, void* d_ws, size_t ws_size,
                              hipStream_t stream) {
    const float* x = (const float*)d_in[0];
    float* out = (float*)d_out;

    // Workspace layout:
    // [0,16)  counter | [16,32) done | sorted ss,sx1,sy1,sx2,sy2 f32[NB] x5 | adj
    char* ws = (char*)d_ws;
    int* counter = (int*)ws;
    int* done = (int*)(ws + 16);
    float* fb  = (float*)(ws + 32);
    float* ss  = fb + 0 * NB;
    float* sx1 = fb + 1 * NB;
    float* sy1 = fb + 2 * NB;
    float* sx2 = fb + 3 * NB;
    float* sy2 = fb + 4 * NB;
    size_t adj_off = 32 + (size_t)5 * NB * 4;          // 184,352 B (8-aligned)
    u64* adj = (u64*)(ws + adj_off);
    long long cap_words = (ws_size > adj_off) ? (long long)((ws_size - adj_off) / 8) : 0;

    k_rank<<<NB / 16, 256, 0, stream>>>(x, ss, sx1, sy1, sx2, sy2, counter, done);
    k_nms<<<KS_BLOCKS, 256, 0, stream>>>(x, out, ss, sx1, sy1, sx2, sy2,
                                         adj, cap_words, counter, done);
}